// Round 24
// baseline (313.881 us; speedup 1.0000x reference)
//
#include <hip/hip_runtime.h>
#include <hip/hip_fp16.h>
#include <math.h>

#define S 1024
#define D 64
#define NBH 64
#define NT 32            // 32-row tiles per bh
#define NBINS 4096
#define NSLICE 16        // private hist slices per bh (one per hist block)
#define TBIN 2458        // bins >= TBIN: exact count; below: 1/4-sampled x4
#define EPS 1e-5f

typedef __attribute__((ext_vector_type(8))) short short8;
typedef __attribute__((ext_vector_type(16))) float floatx16;
typedef __attribute__((ext_vector_type(2))) _Float16 half2v;
typedef __attribute__((ext_vector_type(4))) _Float16 half4v;

__device__ __forceinline__ int binof(float sim) {
    return (int)((sim + 1.0f) * (NBINS / 2));
}

__device__ __forceinline__ unsigned short f2h(float f) {
    return __half_as_ushort(__float2half(f));   // RNE
}

// ---------------- pack Q/K: normalize + fp16 + fragment-major (critical path) ----------------
// block 0 also zeroes the per-bh completion counters used by hist's last-block table.
__global__ __launch_bounds__(256) void pack_qk(
    const float* __restrict__ Q, const float* __restrict__ K,
    unsigned short* __restrict__ Qp, unsigned short* __restrict__ Kp,
    unsigned* __restrict__ cnt)
{
    int b = blockIdx.x;
    int t = threadIdx.x;
    if (b == 0 && t < NBH) cnt[t] = 0;

    int lrow = t >> 3, j = t & 7;
    long long rowArea = (long long)NBH * S;
    long long R = (long long)b * 32 + lrow;
    const float* src; unsigned short* pp;
    if (R < rowArea) { src = Q; pp = Qp; }
    else             { src = K; pp = Kp; R -= rowArea; }
    int bh = (int)(R >> 10), r = (int)(R & 1023);
    int tile = r >> 5, c = r & 31;
    int s = j >> 1, h = j & 1;

    const float* p = src + R * D + j * 8;
    float4 v0 = *(const float4*)(p);
    float4 v1 = *(const float4*)(p + 4);
    float f[8] = {v0.x, v0.y, v0.z, v0.w, v1.x, v1.y, v1.z, v1.w};
    float ss = 0.f;
    #pragma unroll
    for (int e = 0; e < 8; e++) ss += f[e] * f[e];
    ss += __shfl_xor(ss, 1);
    ss += __shfl_xor(ss, 2);
    ss += __shfl_xor(ss, 4);
    float ninv = 1.0f / (sqrtf(ss) + EPS);

    unsigned short hv[8];
    #pragma unroll
    for (int e = 0; e < 8; e++) hv[e] = f2h(f[e] * ninv);

    size_t o = ((((size_t)bh * NT + tile) * 4 + s) * 64 + h * 32 + c) * 8;
    *(uint4*)(pp + o) = *(uint4*)hv;
}

// ---------------- pass 1: hybrid histogram + V-pack + last-block weight table ----------------
// blocks >= 1024: V-pack (2 tiles each). blocks < 1024: hist slice; the 16th
// finisher per bh builds that bh's fp16 weight table (threadfence + counter).
__global__ __launch_bounds__(512) void hist_kernel(
    const unsigned short* __restrict__ Qp, const unsigned short* __restrict__ Kp,
    const float* __restrict__ V, unsigned short* __restrict__ Vp,
    unsigned* __restrict__ hist, unsigned short* __restrict__ wtab,
    unsigned* __restrict__ cnt)
{
    __shared__ unsigned hist_s[NBINS];   // 16 KB (reused as scan buffer in table phase)
    __shared__ unsigned lastflag;
    int bid = blockIdx.x;
    int t = threadIdx.x;

    if (bid >= 1024) {
        // ---- V-pack: Vp[bh][tile][m][lane]x8, shorts rh*4+e = V[k=tile*32+m*8+h*4+e][d=rh*32+c]
        int g = (bid - 1024) * 2 + (t >> 8);   // global V tile index
        int bh = g >> 5;
        int tile = g & 31;
        int tt = t & 255;
        int m = tt >> 6, lane = tt & 63;
        int c = lane & 31, h = lane >> 5;
        int k = tile * 32 + m * 8 + h * 4;
        unsigned short w[8];
        #pragma unroll
        for (int rh = 0; rh < 2; rh++) {
            int d = rh * 32 + c;
            const float* vb = V + ((size_t)bh * S + k) * D + d;
            #pragma unroll
            for (int e = 0; e < 4; e++) w[rh * 4 + e] = f2h(vb[(size_t)e * D]);
        }
        size_t o = ((((size_t)bh * NT + tile) * 4 + m) * 64 + lane) * 8;
        *(uint4*)(Vp + o) = *(uint4*)w;
        return;
    }

    int swzb = (bid & 7) * 128 + (bid >> 3);   // nwg = 1024, XCD-grouped
    int bh  = swzb >> 4;
    int qg  = (swzb >> 2) & 3;
    int kst = swzb & 3;

    #pragma unroll
    for (int i = t; i < NBINS / 4; i += 512) ((uint4*)hist_s)[i] = make_uint4(0,0,0,0);

    int wv = t >> 6, lane = t & 63;
    int qt = qg * 8 + wv;
    const unsigned short* qbp = Qp + (((size_t)bh * NT + qt) * 4) * 64 * 8;
    short8 qf[4];
    #pragma unroll
    for (int s = 0; s < 4; s++)
        qf[s] = *(const short8*)(qbp + ((size_t)s * 64 + lane) * 8);

    __syncthreads();   // hist_s zeroed

    #pragma unroll 2
    for (int it = 0; it < 8; it++) {
        int kt = kst * 8 + it;
        bool full = ((it & 3) == 0);   // kt % 4 == 0
        const unsigned short* kbp = Kp + (((size_t)bh * NT + kt) * 4) * 64 * 8;
        floatx16 sacc = {};
        #pragma unroll
        for (int s = 0; s < 4; s++) {
            short8 kf = *(const short8*)(kbp + ((size_t)s * 64 + lane) * 8);
            sacc = __builtin_amdgcn_mfma_f32_32x32x16_f16(kf, qf[s], sacc, 0, 0, 0);
        }
        if (full) {
            #pragma unroll
            for (int r = 0; r < 16; r++)
                atomicAdd(&hist_s[binof(sacc[r])], 1u);
        } else {
            #pragma unroll
            for (int r = 0; r < 16; r++) {
                int b = binof(sacc[r]);
                if (b >= TBIN) atomicAdd(&hist_s[b], 1u);
            }
        }
    }
    __syncthreads();

    unsigned* hb = hist + ((size_t)bh * NSLICE + qg * 4 + kst) * NBINS;
    #pragma unroll
    for (int i = t; i < NBINS / 4; i += 512)
        ((uint4*)hb)[i] = ((const uint4*)hist_s)[i];

    // ---- completion protocol: last block per bh builds the weight table ----
    __threadfence();                 // release: slice stores visible device-wide
    __syncthreads();
    if (t == 0) lastflag = (atomicAdd(&cnt[bh], 1u) == NSLICE - 1) ? 1u : 0u;
    __syncthreads();
    if (!lastflag) return;
    __threadfence();                 // acquire: see all other slices

    // table: sum 16 slices (8 bins/thread), x4 center, suffix scan, lgamma
    const unsigned* hb0 = hist + (size_t)bh * NSLICE * NBINS;
    unsigned c[8] = {0,0,0,0,0,0,0,0};
    for (int sl = 0; sl < NSLICE; sl++) {
        const unsigned* hs = hb0 + (size_t)sl * NBINS + t * 8;
        uint4 v0 = *(const uint4*)(hs);
        uint4 v1 = *(const uint4*)(hs + 4);
        c[0] += v0.x; c[1] += v0.y; c[2] += v0.z; c[3] += v0.w;
        c[4] += v1.x; c[5] += v1.y; c[6] += v1.z; c[7] += v1.w;
    }
    #pragma unroll
    for (int j = 0; j < 8; j++)
        if (t * 8 + j < TBIN) c[j] *= 4u;

    unsigned tot = 0;
    #pragma unroll
    for (int j = 0; j < 8; j++) tot += c[j];

    __syncthreads();                 // hist_s free for reuse as scan buffer
    unsigned* ssum = hist_s;
    ssum[t] = tot;
    __syncthreads();
    for (int ofs = 1; ofs < 512; ofs <<= 1) {
        unsigned v = ssum[t] + ((t + ofs < 512) ? ssum[t + ofs] : 0u);
        __syncthreads();
        ssum[t] = v;
        __syncthreads();
    }
    unsigned run = (t < 511) ? ssum[t + 1] : 0u;

    unsigned short* wt = wtab + (size_t)bh * NBINS;
    const double ln_n = 13.862943611198906; // ln(1048576)
    #pragma unroll
    for (int i = 7; i >= 0; i--) {
        unsigned ci = c[i];
        float w;
        if (ci) {
            double b = (double)run, e = (double)(run + ci);
            double val = (double)ci * ln_n - (lgamma(e + 1.0) - lgamma(b + 1.0));
            w = (float)(val / (double)ci);
        } else {
            w = (float)(ln_n - log((double)run + 1.0));
        }
        wt[t * 8 + i] = f2h(w);
        run += ci;
    }
}

// ---------------- pass 2 (fused): fp16 scores -> direct-register K=8 PV ----------------
// R21/R23 body: V loads AFTER score chain (VGPR 56), single rowsum fdot2 chain.
__global__ __launch_bounds__(256) void fused_kernel(
    const unsigned short* __restrict__ Qp, const unsigned short* __restrict__ Kp,
    const unsigned short* __restrict__ wtab, const unsigned short* __restrict__ Vp,
    float* __restrict__ out)
{
    __shared__ __align__(16) char smem[8448];   // wt_s (8 KB), later zone (8 KB) + rsz
    unsigned short* wt_s = (unsigned short*)smem;
    float* zone = (float*)smem;
    float* rsz  = (float*)(smem + 32 * 64 * 4);

    int bid = blockIdx.x;
    int swzb = (bid & 7) * 256 + (bid >> 3);   // nwg = 2048, XCD-grouped
    int bh = swzb >> 5;
    int qt = swzb & 31;
    int q0 = qt * 32;
    int t = threadIdx.x;

    const uint4* wg = (const uint4*)(wtab + (size_t)bh * NBINS);
    #pragma unroll
    for (int i = t; i < NBINS / 8; i += 256) ((uint4*)smem)[i] = wg[i];

    int wv = t >> 6, lane = t & 63, c = lane & 31, h = lane >> 5;
    const unsigned short* qbp = Qp + (((size_t)bh * NT + qt) * 4) * 64 * 8;

    short8 qf[4];
    #pragma unroll
    for (int s = 0; s < 4; s++)
        qf[s] = *(const short8*)(qbp + ((size_t)s * 64 + lane) * 8);

    floatx16 oacc0 = {}, oacc1 = {};
    float rs = 0.f;
    const half2v one2 = {(_Float16)1.0f, (_Float16)1.0f};

    __syncthreads();   // wt_s ready

    #pragma unroll 2
    for (int it = 0; it < 8; it++) {
        int kt = wv * 8 + it;
        const unsigned short* kbp = Kp + (((size_t)bh * NT + kt) * 4) * 64 * 8;
        const unsigned short* vpb = Vp + (((size_t)bh * NT + kt) * 4) * 64 * 8;

        floatx16 sacc = {};
        #pragma unroll
        for (int s = 0; s < 4; s++) {
            short8 kf = *(const short8*)(kbp + ((size_t)s * 64 + lane) * 8);
            sacc = __builtin_amdgcn_mfma_f32_32x32x16_f16(kf, qf[s], sacc, 0, 0, 0);
        }

        // V fragments: independent of scores -> issue here, hide under gather
        uint4 B[4];
        #pragma unroll
        for (int m = 0; m < 4; m++)
            B[m] = *(const uint4*)(vpb + ((size_t)m * 64 + lane) * 8);

        unsigned w[16];
        #pragma unroll
        for (int r = 0; r < 16; r++) w[r] = wt_s[binof(sacc[r])];
        unsigned P[8];
        #pragma unroll
        for (int i = 0; i < 8; i++) P[i] = w[2*i] | (w[2*i+1] << 16);
        #pragma unroll
        for (int i = 0; i < 8; i++) {
            union { unsigned u; half2v v; } pv; pv.u = P[i];
            rs = __builtin_amdgcn_fdot2(pv.v, one2, rs, false);
        }

        #pragma unroll
        for (int m = 0; m < 4; m++) {
            union { unsigned u[2]; half4v v; } A, B0, B1;
            A.u[0] = P[2*m]; A.u[1] = P[2*m+1];
            B0.u[0] = B[m].x; B0.u[1] = B[m].y;
            B1.u[0] = B[m].z; B1.u[1] = B[m].w;
            oacc0 = __builtin_amdgcn_mfma_f32_32x32x8f16(A.v, B0.v, oacc0, 0, 0, 0);
            oacc1 = __builtin_amdgcn_mfma_f32_32x32x8f16(A.v, B1.v, oacc1, 0, 0, 0);
        }
    }

    rs += __shfl_xor(rs, 32);   // per-(wave, q=c) rowsum partial

    __syncthreads();   // all waves done with wt_s -> safe to alias zone

    for (int w = 0; w < 4; w++) {
        if (wv == w) {
            if (w == 0) {
                #pragma unroll
                for (int r = 0; r < 16; r++) {
                    int qq = (r & 3) + 8 * (r >> 2) + 4 * h;
                    zone[qq * 64 + c]      = oacc0[r];
                    zone[qq * 64 + 32 + c] = oacc1[r];
                }
                if (h == 0) rsz[c] = rs;
            } else {
                #pragma unroll
                for (int r = 0; r < 16; r++) {
                    int qq = (r & 3) + 8 * (r >> 2) + 4 * h;
                    zone[qq * 64 + c]      += oacc0[r];
                    zone[qq * 64 + 32 + c] += oacc1[r];
                }
                if (h == 0) rsz[c] += rs;
            }
        }
        __syncthreads();
    }

    int q = t >> 3, d0 = (t & 7) * 8;
    float inv = 1.0f / rsz[q];
    float* zp = &zone[q * 64 + d0];
    float4 o0 = *(float4*)(zp);
    float4 o1 = *(float4*)(zp + 4);
    o0.x *= inv; o0.y *= inv; o0.z *= inv; o0.w *= inv;
    o1.x *= inv; o1.y *= inv; o1.z *= inv; o1.w *= inv;
    float* op = out + ((size_t)bh * S + q0 + q) * D + d0;
    *(float4*)(op)     = o0;
    *(float4*)(op + 4) = o1;
}

extern "C" void kernel_launch(void* const* d_in, const int* in_sizes, int n_in,
                              void* d_out, int out_size, void* d_ws, size_t ws_size,
                              hipStream_t stream) {
    const float* Q = (const float*)d_in[0];
    const float* K = (const float*)d_in[1];
    const float* V = (const float*)d_in[2];
    float* out = (float*)d_out;

    char* w = (char*)d_ws;
    size_t off = 0;
    unsigned short* Qp = (unsigned short*)(w + off); off += (size_t)NBH * S * D * 2;
    unsigned short* Kp = (unsigned short*)(w + off); off += (size_t)NBH * S * D * 2;
    unsigned short* Vp = (unsigned short*)(w + off); off += (size_t)NBH * S * D * 2;
    unsigned* hist = (unsigned*)(w + off);           off += (size_t)NBH * NSLICE * NBINS * 4;
    unsigned short* wtab = (unsigned short*)(w + off); off += (size_t)NBH * NBINS * 2;
    unsigned* cnt = (unsigned*)(w + off);            off += (size_t)NBH * 4;

    pack_qk<<<4096, 256, 0, stream>>>(Q, K, Qp, Kp, cnt);
    hist_kernel<<<2048, 512, 0, stream>>>(Qp, Kp, V, Vp, hist, wtab, cnt);
    fused_kernel<<<2048, 256, 0, stream>>>(Qp, Kp, wtab, Vp, out);
}

// Round 25
// 84.668 us; speedup vs baseline: 3.7072x; 3.7072x over previous
//
#include <hip/hip_runtime.h>
#include <hip/hip_fp16.h>
#include <math.h>

#define S 1024
#define D 64
#define NBH 64
#define NT 32            // 32-row tiles per bh
#define NBINS 4096
#define NSLICE 16        // private hist slices per bh (one per hist block)
#define TBIN 2458        // bins >= TBIN: exact count; below: 1/4-sampled x4
#define EPS 1e-5f

typedef __attribute__((ext_vector_type(8))) short short8;
typedef __attribute__((ext_vector_type(16))) float floatx16;
typedef __attribute__((ext_vector_type(2))) _Float16 half2v;
typedef __attribute__((ext_vector_type(4))) _Float16 half4v;

__device__ __forceinline__ int binof(float sim) {
    return (int)((sim + 1.0f) * (NBINS / 2));
}

__device__ __forceinline__ unsigned short f2h(float f) {
    return __half_as_ushort(__float2half(f));   // RNE
}

// ---------------- pack Q/K: normalize + fp16 + fragment-major (critical path) ----------------
__global__ __launch_bounds__(256) void pack_qk(
    const float* __restrict__ Q, const float* __restrict__ K,
    unsigned short* __restrict__ Qp, unsigned short* __restrict__ Kp)
{
    int b = blockIdx.x;
    int t = threadIdx.x;
    int lrow = t >> 3, j = t & 7;
    long long rowArea = (long long)NBH * S;
    long long R = (long long)b * 32 + lrow;
    const float* src; unsigned short* pp;
    if (R < rowArea) { src = Q; pp = Qp; }
    else             { src = K; pp = Kp; R -= rowArea; }
    int bh = (int)(R >> 10), r = (int)(R & 1023);
    int tile = r >> 5, c = r & 31;
    int s = j >> 1, h = j & 1;

    const float* p = src + R * D + j * 8;
    float4 v0 = *(const float4*)(p);
    float4 v1 = *(const float4*)(p + 4);
    float f[8] = {v0.x, v0.y, v0.z, v0.w, v1.x, v1.y, v1.z, v1.w};
    float ss = 0.f;
    #pragma unroll
    for (int e = 0; e < 8; e++) ss += f[e] * f[e];
    ss += __shfl_xor(ss, 1);
    ss += __shfl_xor(ss, 2);
    ss += __shfl_xor(ss, 4);
    float ninv = 1.0f / (sqrtf(ss) + EPS);

    unsigned short hv[8];
    #pragma unroll
    for (int e = 0; e < 8; e++) hv[e] = f2h(f[e] * ninv);

    size_t o = ((((size_t)bh * NT + tile) * 4 + s) * 64 + h * 32 + c) * 8;
    *(uint4*)(pp + o) = *(uint4*)hv;
}

// ---------------- pass 1: hybrid histogram (blocks < 1024) + V-pack (blocks >= 1024) ----------------
__global__ __launch_bounds__(512) void hist_kernel(
    const unsigned short* __restrict__ Qp, const unsigned short* __restrict__ Kp,
    const float* __restrict__ V, unsigned short* __restrict__ Vp,
    unsigned* __restrict__ hist)
{
    __shared__ unsigned hist_s[NBINS];   // 16 KB (unused by V-pack blocks)
    int bid = blockIdx.x;
    int t = threadIdx.x;

    if (bid >= 1024) {
        // ---- V-pack: Vp[bh][tile][m][lane]x8, shorts rh*4+e = V[k=tile*32+m*8+h*4+e][d=rh*32+c]
        int g = (bid - 1024) * 2 + (t >> 8);   // global V tile index
        int bh = g >> 5;
        int tile = g & 31;
        int tt = t & 255;
        int m = tt >> 6, lane = tt & 63;
        int c = lane & 31, h = lane >> 5;
        int k = tile * 32 + m * 8 + h * 4;
        unsigned short w[8];
        #pragma unroll
        for (int rh = 0; rh < 2; rh++) {
            int d = rh * 32 + c;
            const float* vb = V + ((size_t)bh * S + k) * D + d;
            #pragma unroll
            for (int e = 0; e < 4; e++) w[rh * 4 + e] = f2h(vb[(size_t)e * D]);
        }
        size_t o = ((((size_t)bh * NT + tile) * 4 + m) * 64 + lane) * 8;
        *(uint4*)(Vp + o) = *(uint4*)w;
        return;
    }

    int swzb = (bid & 7) * 128 + (bid >> 3);   // nwg = 1024, XCD-grouped
    int bh  = swzb >> 4;
    int qg  = (swzb >> 2) & 3;
    int kst = swzb & 3;

    #pragma unroll
    for (int i = t; i < NBINS / 4; i += 512) ((uint4*)hist_s)[i] = make_uint4(0,0,0,0);

    int wv = t >> 6, lane = t & 63;
    int qt = qg * 8 + wv;
    const unsigned short* qbp = Qp + (((size_t)bh * NT + qt) * 4) * 64 * 8;
    short8 qf[4];
    #pragma unroll
    for (int s = 0; s < 4; s++)
        qf[s] = *(const short8*)(qbp + ((size_t)s * 64 + lane) * 8);

    __syncthreads();   // hist_s zeroed

    #pragma unroll 2
    for (int it = 0; it < 8; it++) {
        int kt = kst * 8 + it;
        bool full = ((it & 3) == 0);   // kt % 4 == 0
        const unsigned short* kbp = Kp + (((size_t)bh * NT + kt) * 4) * 64 * 8;
        floatx16 sacc = {};
        #pragma unroll
        for (int s = 0; s < 4; s++) {
            short8 kf = *(const short8*)(kbp + ((size_t)s * 64 + lane) * 8);
            sacc = __builtin_amdgcn_mfma_f32_32x32x16_f16(kf, qf[s], sacc, 0, 0, 0);
        }
        if (full) {
            #pragma unroll
            for (int r = 0; r < 16; r++)
                atomicAdd(&hist_s[binof(sacc[r])], 1u);
        } else {
            #pragma unroll
            for (int r = 0; r < 16; r++) {
                int b = binof(sacc[r]);
                if (b >= TBIN) atomicAdd(&hist_s[b], 1u);
            }
        }
    }
    __syncthreads();

    unsigned* hb = hist + ((size_t)bh * NSLICE + qg * 4 + kst) * NBINS;
    #pragma unroll
    for (int i = t; i < NBINS / 4; i += 512)
        ((uint4*)hb)[i] = ((const uint4*)hist_s)[i];
}

// ---------------- weight table (fp16): sum slices, x4 center, scan + lgamma ----------------
__global__ __launch_bounds__(1024) void table_kernel(
    const unsigned* __restrict__ hist, unsigned short* __restrict__ wtab)
{
    __shared__ unsigned ssum[1024];
    int tid = threadIdx.x;
    const unsigned* h = hist + (size_t)blockIdx.x * NSLICE * NBINS;
    unsigned short* wt = wtab + (size_t)blockIdx.x * NBINS;

    unsigned c[4] = {0, 0, 0, 0};
    #pragma unroll
    for (int sl = 0; sl < NSLICE; sl++) {
        uint4 v = *(const uint4*)(h + (size_t)sl * NBINS + tid * 4);
        c[0] += v.x; c[1] += v.y; c[2] += v.z; c[3] += v.w;
    }
    #pragma unroll
    for (int j = 0; j < 4; j++)
        if (tid * 4 + j < TBIN) c[j] *= 4u;

    unsigned tot = c[0] + c[1] + c[2] + c[3];
    ssum[tid] = tot;
    __syncthreads();
    for (int ofs = 1; ofs < 1024; ofs <<= 1) {
        unsigned v = ssum[tid] + ((tid + ofs < 1024) ? ssum[tid + ofs] : 0u);
        __syncthreads();
        ssum[tid] = v;
        __syncthreads();
    }
    unsigned run = (tid < 1023) ? ssum[tid + 1] : 0u;

    const double ln_n = 13.862943611198906; // ln(1048576)
    #pragma unroll
    for (int i = 3; i >= 0; i--) {
        unsigned ci = c[i];
        float w;
        if (ci) {
            double b = (double)run, e = (double)(run + ci);
            double val = (double)ci * ln_n - (lgamma(e + 1.0) - lgamma(b + 1.0));
            w = (float)(val / (double)ci);
        } else {
            w = (float)(ln_n - log((double)run + 1.0));
        }
        wt[tid * 4 + i] = f2h(w);
        run += ci;
    }
}

// ---------------- pass 2 (fused): fp16 scores -> direct-register K=8 PV ----------------
// V loads AFTER score chain (VGPR 56), single rowsum fdot2 chain.
__global__ __launch_bounds__(256) void fused_kernel(
    const unsigned short* __restrict__ Qp, const unsigned short* __restrict__ Kp,
    const unsigned short* __restrict__ wtab, const unsigned short* __restrict__ Vp,
    float* __restrict__ out)
{
    __shared__ __align__(16) char smem[8448];   // wt_s (8 KB), later zone (8 KB) + rsz
    unsigned short* wt_s = (unsigned short*)smem;
    float* zone = (float*)smem;
    float* rsz  = (float*)(smem + 32 * 64 * 4);

    int bid = blockIdx.x;
    int swzb = (bid & 7) * 256 + (bid >> 3);   // nwg = 2048, XCD-grouped
    int bh = swzb >> 5;
    int qt = swzb & 31;
    int q0 = qt * 32;
    int t = threadIdx.x;

    const uint4* wg = (const uint4*)(wtab + (size_t)bh * NBINS);
    #pragma unroll
    for (int i = t; i < NBINS / 8; i += 256) ((uint4*)smem)[i] = wg[i];

    int wv = t >> 6, lane = t & 63, c = lane & 31, h = lane >> 5;
    const unsigned short* qbp = Qp + (((size_t)bh * NT + qt) * 4) * 64 * 8;

    short8 qf[4];
    #pragma unroll
    for (int s = 0; s < 4; s++)
        qf[s] = *(const short8*)(qbp + ((size_t)s * 64 + lane) * 8);

    floatx16 oacc0 = {}, oacc1 = {};
    float rs = 0.f;
    const half2v one2 = {(_Float16)1.0f, (_Float16)1.0f};

    __syncthreads();   // wt_s ready

    #pragma unroll 2
    for (int it = 0; it < 8; it++) {
        int kt = wv * 8 + it;
        const unsigned short* kbp = Kp + (((size_t)bh * NT + kt) * 4) * 64 * 8;
        const unsigned short* vpb = Vp + (((size_t)bh * NT + kt) * 4) * 64 * 8;

        floatx16 sacc = {};
        #pragma unroll
        for (int s = 0; s < 4; s++) {
            short8 kf = *(const short8*)(kbp + ((size_t)s * 64 + lane) * 8);
            sacc = __builtin_amdgcn_mfma_f32_32x32x16_f16(kf, qf[s], sacc, 0, 0, 0);
        }

        // V fragments: independent of scores -> issue here, hide under gather
        uint4 B[4];
        #pragma unroll
        for (int m = 0; m < 4; m++)
            B[m] = *(const uint4*)(vpb + ((size_t)m * 64 + lane) * 8);

        unsigned w[16];
        #pragma unroll
        for (int r = 0; r < 16; r++) w[r] = wt_s[binof(sacc[r])];
        unsigned P[8];
        #pragma unroll
        for (int i = 0; i < 8; i++) P[i] = w[2*i] | (w[2*i+1] << 16);
        #pragma unroll
        for (int i = 0; i < 8; i++) {
            union { unsigned u; half2v v; } pv; pv.u = P[i];
            rs = __builtin_amdgcn_fdot2(pv.v, one2, rs, false);
        }

        #pragma unroll
        for (int m = 0; m < 4; m++) {
            union { unsigned u[2]; half4v v; } A, B0, B1;
            A.u[0] = P[2*m]; A.u[1] = P[2*m+1];
            B0.u[0] = B[m].x; B0.u[1] = B[m].y;
            B1.u[0] = B[m].z; B1.u[1] = B[m].w;
            oacc0 = __builtin_amdgcn_mfma_f32_32x32x8f16(A.v, B0.v, oacc0, 0, 0, 0);
            oacc1 = __builtin_amdgcn_mfma_f32_32x32x8f16(A.v, B1.v, oacc1, 0, 0, 0);
        }
    }

    rs += __shfl_xor(rs, 32);   // per-(wave, q=c) rowsum partial

    __syncthreads();   // all waves done with wt_s -> safe to alias zone

    for (int w = 0; w < 4; w++) {
        if (wv == w) {
            if (w == 0) {
                #pragma unroll
                for (int r = 0; r < 16; r++) {
                    int qq = (r & 3) + 8 * (r >> 2) + 4 * h;
                    zone[qq * 64 + c]      = oacc0[r];
                    zone[qq * 64 + 32 + c] = oacc1[r];
                }
                if (h == 0) rsz[c] = rs;
            } else {
                #pragma unroll
                for (int r = 0; r < 16; r++) {
                    int qq = (r & 3) + 8 * (r >> 2) + 4 * h;
                    zone[qq * 64 + c]      += oacc0[r];
                    zone[qq * 64 + 32 + c] += oacc1[r];
                }
                if (h == 0) rsz[c] += rs;
            }
        }
        __syncthreads();
    }

    int q = t >> 3, d0 = (t & 7) * 8;
    float inv = 1.0f / rsz[q];
    float* zp = &zone[q * 64 + d0];
    float4 o0 = *(float4*)(zp);
    float4 o1 = *(float4*)(zp + 4);
    o0.x *= inv; o0.y *= inv; o0.z *= inv; o0.w *= inv;
    o1.x *= inv; o1.y *= inv; o1.z *= inv; o1.w *= inv;
    float* op = out + ((size_t)bh * S + q0 + q) * D + d0;
    *(float4*)(op)     = o0;
    *(float4*)(op + 4) = o1;
}

extern "C" void kernel_launch(void* const* d_in, const int* in_sizes, int n_in,
                              void* d_out, int out_size, void* d_ws, size_t ws_size,
                              hipStream_t stream) {
    const float* Q = (const float*)d_in[0];
    const float* K = (const float*)d_in[1];
    const float* V = (const float*)d_in[2];
    float* out = (float*)d_out;

    char* w = (char*)d_ws;
    size_t off = 0;
    unsigned short* Qp = (unsigned short*)(w + off); off += (size_t)NBH * S * D * 2;
    unsigned short* Kp = (unsigned short*)(w + off); off += (size_t)NBH * S * D * 2;
    unsigned short* Vp = (unsigned short*)(w + off); off += (size_t)NBH * S * D * 2;
    unsigned* hist = (unsigned*)(w + off);           off += (size_t)NBH * NSLICE * NBINS * 4;
    unsigned short* wtab = (unsigned short*)(w + off); off += (size_t)NBH * NBINS * 2;

    pack_qk<<<4096, 256, 0, stream>>>(Q, K, Qp, Kp);
    hist_kernel<<<2048, 512, 0, stream>>>(Qp, Kp, V, Vp, hist);
    table_kernel<<<NBH, 1024, 0, stream>>>(hist, wtab);
    fused_kernel<<<2048, 256, 0, stream>>>(Qp, Kp, wtab, Vp, out);
}